// Round 7
// baseline (214.140 us; speedup 1.0000x reference)
//
#include <hip/hip_runtime.h>
#include <stdint.h>

#define B_N   8
#define C_N   256
#define H_N   96
#define W_N   128
#define NCK   8          // C_N / 32
#define ND    21
#define NK    (ND * ND)  // 441

typedef __attribute__((ext_vector_type(8))) short short8;
typedef __attribute__((ext_vector_type(4))) float f32x4;

__device__ __forceinline__ uint32_t f2bf(float f) {
  uint32_t u = __builtin_bit_cast(uint32_t, f);
  return (u + 0x7fffu + ((u >> 16) & 1u)) >> 16;   // RNE
}
__device__ __forceinline__ uint32_t packbf(float lo, float hi) {
  return f2bf(lo) | (f2bf(hi) << 16);
}
__device__ __forceinline__ void async16(void* lds_dst, const void* gsrc) {
  __builtin_amdgcn_global_load_lds(
      (const __attribute__((address_space(1))) void*)gsrc,
      (__attribute__((address_space(3))) void*)lds_dst, 16, 0, 0);
}

// ---------------- merged prepass: fp32 NCHW -> bf16 fragment-linear layouts ----------------
// Apre per (bi,ck): 8 KB.  u32 idx = ((t*2+p)<<8) + lane*4 + e2 ; lane = m + 16*kg
// Bpre per (by,ck): 12 KB. u32 idx = ((s*2+p)<<8) + lane*4 + e2 ; x = 32s+2m-20+p, halo zeroed
__global__ __launch_bounds__(256) void prep(const float* __restrict__ in1,
                                            const float* __restrict__ in2,
                                            unsigned short* __restrict__ Apre,
                                            unsigned short* __restrict__ Bpre) {
  __shared__ float tile[32][W_N + 1];
  int blk = blockIdx.x;
  bool isA = blk < 6144;
  int rblk = isA ? blk : blk - 6144;
  int ck = rblk & 7, bi = rblk >> 3;
  int b = bi / H_N, row = bi % H_N;
  const float* src = (isA ? in1 : in2) + ((size_t)(b * C_N + ck * 32) * H_N + row) * W_N;
  int tid = threadIdx.x;
  for (int idx = tid; idx < 32 * W_N; idx += 256) {
    int c = idx >> 7, j = idx & 127;
    tile[c][j] = src[(size_t)c * (H_N * W_N) + j];
  }
  __syncthreads();
  if (isA) {
    uint32_t* dst = (uint32_t*)Apre + (size_t)rblk * 2048;
    for (int q = tid; q < 2048; q += 256) {
      int e2 = q & 3, ln = (q >> 2) & 63, tp = q >> 8;
      int t = tp >> 1, p = tp & 1;
      int m = ln & 15, kg = ln >> 4;
      int c0 = kg * 8 + 2 * e2;
      int j = 32 * t + 2 * m + p;
      dst[q] = packbf(tile[c0][j], tile[c0 + 1][j]);
    }
  } else {
    uint32_t* dst = (uint32_t*)Bpre + (size_t)rblk * 3072;
    for (int q = tid; q < 3072; q += 256) {
      int e2 = q & 3, ln = (q >> 2) & 63, sp = q >> 8;
      int s = sp >> 1, p = sp & 1;
      int m = ln & 15, kg = ln >> 4;
      int c0 = kg * 8 + 2 * e2;
      int x = 32 * s + 2 * m - 20 + p;
      dst[q] = ((unsigned)x < 128u) ? packbf(tile[c0][x], tile[c0 + 1][x]) : 0u;
    }
  }
}

#define MF(a, b, c) __builtin_amdgcn_mfma_f32_16x16x32_bf16(a, b, c, 0, 0, 0)
#define SB0() __builtin_amdgcn_sched_barrier(0)
#define BAR() __builtin_amdgcn_s_barrier()
#define WAITV7() asm volatile("s_waitcnt vmcnt(7)" ::: "memory")
#define WAITV0() asm volatile("s_waitcnt vmcnt(0)" ::: "memory")

// 6 MFMAs of one g: ss-operands S0..S3 (s = 2th+ss)
#define MF6(A0, A1, S0, S1, S2, S3, GI) do {                    \
  acc[0][GI][0] = MF(A0, S0, acc[0][GI][0]);                    \
  acc[0][GI][1] = MF(A0, S1, acc[0][GI][1]);                    \
  acc[1][GI][0] = MF(A1, S1, acc[1][GI][0]);                    \
  acc[0][GI][2] = MF(A0, S2, acc[0][GI][2]);                    \
  acc[1][GI][1] = MF(A1, S2, acc[1][GI][1]);                    \
  acc[1][GI][2] = MF(A1, S3, acc[1][GI][2]);                    \
} while (0)

// issue chunk CK: 2 LDS fills + 2 A-frag loads + 3 glob-B-frag loads = 7 VMEM ops
#define ISSUE(AV0, AV1, GV0, GV1, GV2, CK) do {                                   \
  async16(lds + (((CK) & 1) ? dst0b1 : dst0b0), src0 + (size_t)(CK) * 12288);     \
  async16(lds + (((CK) & 1) ? dst1b1 : dst1b0), src1 + (size_t)(CK) * 12288);     \
  AV0 = *(const short8*)(Ap + (size_t)(CK) * 8192);                               \
  AV1 = *(const short8*)(Ap + (size_t)(CK) * 8192 + 2048);                        \
  GV0 = *(const short8*)(bg0 + (size_t)(CK) * 12288);                             \
  GV1 = *(const short8*)(bg1 + (size_t)(CK) * 12288);                             \
  GV2 = *(const short8*)(bg2 + (size_t)(CK) * 12288);                             \
} while (0)

// consume chunk CK: per g — 3 ds_read_b128 + glob-edge frag + 6 MFMAs (g-batched for regs)
#define COMPG(AV0, AV1, GV, YV, GI, CK) do {                                      \
  const char* cb_ = lds + ((CK) & 1) * 24576 + dsb + (GI) * 8192;                 \
  short8 q0 = *(const short8*)(cb_);                                              \
  short8 q1 = *(const short8*)(cb_ + 2048);                                       \
  short8 q2 = *(const short8*)(cb_ + 4096);                                       \
  short8 eg = (YV) ? (GV) : z8;                                                   \
  if (th == 0) { MF6(AV0, AV1, eg, q0, q1, q2, GI); }                             \
  else         { MF6(AV0, AV1, q0, q1, q2, eg, GI); }                             \
} while (0)

#define COMP(AV0, AV1, GV0, GV1, GV2, CK) do {                                    \
  if (act) {                                                                      \
    COMPG(AV0, AV1, GV0, yv0, 0, CK);                                             \
    COMPG(AV0, AV1, GV1, yv1, 1, CK);                                             \
    COMPG(AV0, AV1, GV2, yv2, 2, CK);                                             \
  }                                                                               \
} while (0)

#define STEPK(IA0, IA1, IG0, IG1, IG2, KN, CA0, CA1, CG0, CG1, CG2, KC) do {      \
  ISSUE(IA0, IA1, IG0, IG1, IG2, KN);                                             \
  SB0(); WAITV7(); SB0(); BAR(); SB0();                                           \
  COMP(CA0, CA1, CG0, CG1, CG2, KC);                                              \
  SB0(); BAR(); SB0();                                                            \
} while (0)

// ---------------- main: chain-block, split-pipe fragments, counted-vmcnt schedule ----------
// Chain Y = i + 6*gidx - 20: 3 elements (rr) share B rows {Y,Y+2,Y+4}.
// LDS: [0,24576) buf0 {3 g}×8KB (units s=1..4 ×p), [24576,49152) buf1, [49152,50176) dump.
// Per wave-chunk: 2 fills (1KB), A×2 + glob-edge-B×3 direct global, 9 ds_read_b128, 18 MFMA.
__global__ __launch_bounds__(768, 3) void corr_main(const unsigned short* __restrict__ Apre,
                                                    const unsigned short* __restrict__ Bpre,
                                                    float* __restrict__ out) {
  __shared__ __align__(16) char lds[50176];

  int h = blockIdx.x;
  int b = h & 7, blk = h >> 3;          // one batch image per XCD
  int Y, pos;
  if (blk < 18)       { Y = blk - 20;                pos = 0; }
  else if (blk < 54)  { int t = blk - 18;  Y = -2 + (t >> 1); pos = t & 1; }
  else if (blk < 234) { int t = blk - 54;  Y = 16 + t / 3;    pos = t % 3; }
  else if (blk < 270) { int t = blk - 234; Y = 76 + (t >> 1); pos = t & 1; }
  else                { Y = 94 + (blk - 270);        pos = 0; }
  int g_min = (Y > 75) ? (Y - 70) / 6 : 0;
  int g_max = (Y + 20) / 6; if (g_max > 6) g_max = 6;

  int tid = threadIdx.x;
  int lane = tid & 63, w = tid >> 6;    // 12 waves: (rr, p, th)
  int rr = w >> 2, sub = w & 3;
  int p = sub & 1, th = sub >> 1;
  int m = lane & 15, kg = lane >> 4;

  int gidx = g_min + pos * 3 + rr;
  bool act = gidx <= g_max;
  int i_el = Y + 20 - 6 * gidx;
  int dyb = 3 * gidx;

  bool yv0, yv1, yv2;
  const char* brow_s[3];
  {
    bool yv[3];
#pragma unroll
    for (int g = 0; g < 3; ++g) {
      int y = Y + 2 * g;
      yv[g] = (unsigned)y < (unsigned)H_N;
      brow_s[g] = (const char*)Bpre + (size_t)((b * H_N + (yv[g] ? y : 0)) * NCK) * 12288;
    }
    yv0 = yv[0]; yv1 = yv[1]; yv2 = yv[2];
  }

  // fill assignments: 24 fills = 3 g-rows x 8 units (s=1..4, p=0..1 -> bytes [2048,10240))
  int f0 = 2 * w, f1 = 2 * w + 1;
  int g0 = f0 >> 3, u0 = f0 & 7, g1 = f1 >> 3, u1 = f1 & 7;
  bool v0 = (g0 == 0) ? yv0 : (g0 == 1) ? yv1 : yv2;
  bool v1 = (g1 == 0) ? yv0 : (g1 == 1) ? yv1 : yv2;
  int dst0b0 = v0 ? (g0 * 8192 + u0 * 1024 + lane * 16) : (49152 + lane * 16);
  int dst0b1 = v0 ? (dst0b0 + 24576) : dst0b0;
  int dst1b0 = v1 ? (g1 * 8192 + u1 * 1024 + lane * 16) : (49152 + lane * 16);
  int dst1b1 = v1 ? (dst1b0 + 24576) : dst1b0;
  const char* src0 = brow_s[g0] + 2048 + u0 * 1024 + lane * 16;
  const char* src1 = brow_s[g1] + 2048 + u1 * 1024 + lane * 16;

  const char* Ap = (const char*)Apre + (size_t)(b * H_N + (act ? i_el : 0)) * 65536
                   + ((4 * th + p) << 10) + lane * 16;
  int gunit = (th ? 10 : 0) + p;        // glob edge s-tile: th0->s0, th1->s5
  const char* bg0 = brow_s[0] + gunit * 1024 + lane * 16;
  const char* bg1 = brow_s[1] + gunit * 1024 + lane * 16;
  const char* bg2 = brow_s[2] + gunit * 1024 + lane * 16;

  int dsb = (p + (th ? 2 : 0)) * 1024 + lane * 16;   // staged ds base (s=2th+ss -> +ss*2048)

  f32x4 acc[2][3][3];
#pragma unroll
  for (int a0i = 0; a0i < 2; ++a0i)
#pragma unroll
    for (int a1i = 0; a1i < 3; ++a1i)
#pragma unroll
      for (int a2i = 0; a2i < 3; ++a2i) acc[a0i][a1i][a2i] = {0.f, 0.f, 0.f, 0.f};

  short8 z8 = {};

  // zero invalid g slots once (fills for those rows are redirected to dump forever)
  {
    bool yv[3] = {yv0, yv1, yv2};
#pragma unroll
    for (int g = 0; g < 3; ++g) {
      if (!yv[g]) {
        for (int idx = tid; idx < 1024; idx += 768) {
          int bs = idx >> 9, of = (idx & 511) * 16;
          *(short8*)(lds + bs * 24576 + g * 8192 + of) = z8;
        }
      }
    }
  }
  asm volatile("s_waitcnt lgkmcnt(0)" ::: "memory");

  short8 aP0, aP1, gP0, gP1, gP2, aQ0, aQ1, gQ0, gQ1, gQ2;

  ISSUE(aP0, aP1, gP0, gP1, gP2, 0);
  STEPK(aQ0, aQ1, gQ0, gQ1, gQ2, 1, aP0, aP1, gP0, gP1, gP2, 0);
  STEPK(aP0, aP1, gP0, gP1, gP2, 2, aQ0, aQ1, gQ0, gQ1, gQ2, 1);
  STEPK(aQ0, aQ1, gQ0, gQ1, gQ2, 3, aP0, aP1, gP0, gP1, gP2, 2);
  STEPK(aP0, aP1, gP0, gP1, gP2, 4, aQ0, aQ1, gQ0, gQ1, gQ2, 3);
  STEPK(aQ0, aQ1, gQ0, gQ1, gQ2, 5, aP0, aP1, gP0, gP1, gP2, 4);
  STEPK(aP0, aP1, gP0, gP1, gP2, 6, aQ0, aQ1, gQ0, gQ1, gQ2, 5);
  STEPK(aQ0, aQ1, gQ0, gQ1, gQ2, 7, aP0, aP1, gP0, gP1, gP2, 6);
  // tail: chunk 7 (set Q)
  WAITV0(); SB0(); BAR(); SB0();
  COMP(aQ0, aQ1, gQ0, gQ1, gQ2, 7);
  __syncthreads();   // all LDS reads done before epilogue reuse

  // ---- epilogue: per-rr band-extract via LDS, coalesced stores
  float* outl = (float*)(lds + rr * 11072);    // [21][129] f32 region per rr-group
  int gt = sub * 64 + lane;
#pragma unroll
  for (int g = 0; g < 3; ++g) {
    if (act) {
#pragma unroll
      for (int tt = 0; tt < 2; ++tt) {
        int t = 2 * th + tt;
#pragma unroll
        for (int dl = 0; dl < 3; ++dl) {
#pragma unroll
          for (int r = 0; r < 4; ++r) {
            int a_ = kg * 4 + r;
            int dxi = 16 * dl + m - a_;
            if (dxi >= 0 && dxi <= 20) {
              int j = 2 * (16 * t + a_) + p;
              outl[dxi * 129 + j] = acc[tt][g][dl][r];
            }
          }
        }
      }
    }
    __syncthreads();
    if (act) {
      int dyi = dyb + g;
      size_t obase = ((size_t)(b * NK + dyi * ND) * H_N + i_el) * W_N;
      for (int idx = gt; idx < ND * W_N; idx += 256) {
        int dxi = idx >> 7, j = idx & 127;
        out[obase + (size_t)dxi * (H_N * W_N) + j] = outl[dxi * 129 + j];
      }
    }
    __syncthreads();
  }
}

// ---------------- fallback (only if workspace too small) ----------------
__global__ void corr_naive(const float* __restrict__ in1, const float* __restrict__ in2,
                           float* __restrict__ out) {
  size_t o = (size_t)blockIdx.x * 256 + threadIdx.x;
  const size_t total = (size_t)B_N * NK * H_N * W_N;
  if (o >= total) return;
  int j = o & 127;
  int i = (int)((o >> 7) % H_N);
  int k = (int)((o / ((size_t)H_N * W_N)) % NK);
  int b = (int)(o / ((size_t)NK * H_N * W_N));
  int dyi = k / ND, dxi = k % ND;
  int y = i + 2 * dyi - 20, x = j + 2 * dxi - 20;
  float s = 0.f;
  if ((unsigned)y < (unsigned)H_N && (unsigned)x < (unsigned)W_N) {
    const float* p1 = in1 + ((size_t)b * C_N * H_N + i) * W_N + j;
    const float* p2 = in2 + ((size_t)b * C_N * H_N + y) * W_N + x;
    for (int c = 0; c < C_N; ++c)
      s += p1[(size_t)c * H_N * W_N] * p2[(size_t)c * H_N * W_N];
  }
  out[o] = s;
}

extern "C" void kernel_launch(void* const* d_in, const int* in_sizes, int n_in,
                              void* d_out, int out_size, void* d_ws, size_t ws_size,
                              hipStream_t stream) {
  const float* in1 = (const float*)d_in[0];
  const float* in2 = (const float*)d_in[1];
  float* out = (float*)d_out;

  const size_t A_BYTES = (size_t)6144 * 8192;    // 50,331,648
  const size_t B_BYTES = (size_t)6144 * 12288;   // 75,497,472
  if (ws_size < A_BYTES + B_BYTES) {
    size_t total = (size_t)B_N * NK * H_N * W_N;
    corr_naive<<<(int)((total + 255) / 256), 256, 0, stream>>>(in1, in2, out);
    return;
  }
  unsigned short* Apre = (unsigned short*)d_ws;
  unsigned short* Bpre = (unsigned short*)((char*)d_ws + A_BYTES);

  prep<<<12288, 256, 0, stream>>>(in1, in2, Apre, Bpre);
  corr_main<<<2304, 768, 0, stream>>>(Apre, Bpre, out);
}